// Round 7
// baseline (521.937 us; speedup 1.0000x reference)
//
#include <hip/hip_runtime.h>
#include <hip/hip_bf16.h>

typedef __hip_bfloat16 bf16;
typedef __attribute__((ext_vector_type(8))) short bf16x8;   // 8 bf16 = 4 VGPRs
typedef __attribute__((ext_vector_type(4))) float f32x4;

constexpr int DD = 128;     // feature dim
constexpr int NAC = 8192;   // actors
constexpr int NND = 65536;  // nodes
constexpr int NEG = 262144; // edges
constexpr int AP = 136;     // Abuf pitch: 272B rows, 16B-aligned; 68 dw === 4 mod 32 -> 2-way alias (free)
constexpr int TSZ = 16384;  // packed W tile elems (128x128)
constexpr float GN_EPS = 1e-5f;

#define DEVINL __device__ __attribute__((always_inline)) static inline

DEVINL float bf2f(short s) { return __uint_as_float(((unsigned)(unsigned short)s) << 16); }

// ---- K=128 GEMM, B from PRE-SWIZZLED global (lane-uniform + lane*16B -> coalesced).
//      C[32 rows x 128 ch] += A[32x128] * W^T. Wave-private, zero barriers. ----
DEVINL void gemm_gB(const bf16* __restrict__ Wp, const bf16* Aw,
                    f32x4 (&acc)[2][8], int lane, int quad, int l16)
{
    const bf16* Wl = Wp + lane * 8;
    #pragma unroll
    for (int ks = 0; ks < 4; ks++) {
        bf16x8 a0 = *(const bf16x8*)(Aw + l16 * AP + ks * 32 + quad * 8);
        bf16x8 a1 = *(const bf16x8*)(Aw + (16 + l16) * AP + ks * 32 + quad * 8);
        #pragma unroll
        for (int nt = 0; nt < 8; nt++) {
            bf16x8 b = *(const bf16x8*)(Wl + (ks * 8 + nt) * 512);
            acc[0][nt] = __builtin_amdgcn_mfma_f32_16x16x32_bf16(a0, b, acc[0][nt], 0, 0, 0);
            acc[1][nt] = __builtin_amdgcn_mfma_f32_16x16x32_bf16(a1, b, acc[1][nt], 0, 0, 0);
        }
    }
}

DEVINL void zero_acc(f32x4 (&acc)[2][8])
{
    #pragma unroll
    for (int i = 0; i < 2; i++)
        #pragma unroll
        for (int j = 0; j < 8; j++)
            acc[i][j] = f32x4{0.f, 0.f, 0.f, 0.f};
}

// ---- in-register GroupNorm + ReLU -> wave-private Abuf ----
DEVINL void gn_relu(f32x4 (&acc)[2][8], const float (&gv)[8], const float (&bv)[8],
                    bf16* Aw, int quad, int l16)
{
    #pragma unroll
    for (int mt = 0; mt < 2; mt++) {
        #pragma unroll
        for (int r = 0; r < 4; r++) {
            float s1 = 0.f, s2 = 0.f;
            #pragma unroll
            for (int nt = 0; nt < 8; nt++) { float v = acc[mt][nt][r]; s1 += v; s2 += v * v; }
            #pragma unroll
            for (int m = 1; m < 16; m <<= 1) { s1 += __shfl_xor(s1, m, 64); s2 += __shfl_xor(s2, m, 64); }
            float mean = s1 * (1.f / 128.f);
            float sc = rsqrtf(s2 * (1.f / 128.f) - mean * mean + GN_EPS);
            int row = mt * 16 + quad * 4 + r;
            #pragma unroll
            for (int nt = 0; nt < 8; nt++) {
                float y = (acc[mt][nt][r] - mean) * sc * gv[nt] + bv[nt];
                Aw[row * AP + nt * 16 + l16] = __float2bfloat16(fmaxf(y, 0.f));
            }
        }
    }
}

// ---- fp32 rows -> wave-private Abuf bf16 ----
DEVINL void stage_rows_f32(const float* __restrict__ src, int r0, int lane, bf16* Aw)
{
    int half = lane >> 5, c4 = (lane & 31) * 4;
    #pragma unroll
    for (int it = 0; it < 16; it++) {
        int rr = it * 2 + half;
        float4 v = *(const float4*)(src + (size_t)(r0 + rr) * DD + c4);
        short4 p;
        bf16 t0 = __float2bfloat16(v.x); p.x = *(short*)&t0;
        bf16 t1 = __float2bfloat16(v.y); p.y = *(short*)&t1;
        bf16 t2 = __float2bfloat16(v.z); p.z = *(short*)&t2;
        bf16 t3 = __float2bfloat16(v.w); p.w = *(short*)&t3;
        *(short4*)(Aw + rr * AP + c4) = p;
    }
}

// ---- pack all weight tiles fp32 -> bf16 in B-fragment-swizzled order.
//      P[tile][ks][nt][lane][j] = W[nt*16+(lane&15)][ks*32+(lane>>4)*8+j]
//      tiles per block: 0=dist1 1=query 2=ctx0d 3=ctx0q 4=ctx0n 5=ctx1 6=agt 7=lin ----
__global__ void pack_w_kernel(const float* __restrict__ d1, const float* __restrict__ qw,
                              const float* __restrict__ c0, const float* __restrict__ c1,
                              const float* __restrict__ ag, const float* __restrict__ li,
                              bf16* __restrict__ dst)
{
    int gid = blockIdx.x * blockDim.x + threadIdx.x;   // 32768 groups of 8
    int tile = gid >> 11, g = gid & 2047;
    int i = tile >> 3, tt = tile & 7;
    int ks = g >> 9, rem = g & 511, nt = rem >> 6, lane = rem & 63;
    int row = nt * 16 + (lane & 15), col = ks * 32 + (lane >> 4) * 8;
    const float* src; int stride;
    switch (tt) {
        case 0: src = d1 + i * 16384; stride = 128; break;
        case 1: src = qw + i * 16384; stride = 128; break;
        case 2: src = c0 + i * 49152;       stride = 384; break;
        case 3: src = c0 + i * 49152 + 128; stride = 384; break;
        case 4: src = c0 + i * 49152 + 256; stride = 384; break;
        case 5: src = c1 + i * 16384; stride = 128; break;
        case 6: src = ag + i * 16384; stride = 128; break;
        default: src = li + i * 16384; stride = 128; break;
    }
    const float* s = src + (size_t)row * stride + col;
    float4 v0 = *(const float4*)s, v1 = *(const float4*)(s + 4);
    bf16x8 pk;
    bf16 t;
    t = __float2bfloat16(v0.x); pk[0] = *(short*)&t;
    t = __float2bfloat16(v0.y); pk[1] = *(short*)&t;
    t = __float2bfloat16(v0.z); pk[2] = *(short*)&t;
    t = __float2bfloat16(v0.w); pk[3] = *(short*)&t;
    t = __float2bfloat16(v1.x); pk[4] = *(short*)&t;
    t = __float2bfloat16(v1.y); pk[5] = *(short*)&t;
    t = __float2bfloat16(v1.z); pk[6] = *(short*)&t;
    t = __float2bfloat16(v1.w); pk[7] = *(short*)&t;
    *(bf16x8*)(dst + (size_t)gid * 8) = pk;
}

// =================== counting sort of edges by hi ===================
__global__ void zero_cnt_kernel(int* __restrict__ cnt)
{
    cnt[blockIdx.x * blockDim.x + threadIdx.x] = 0;   // 8192 ints
}

__global__ void hist_kernel(const int* __restrict__ hi, int* __restrict__ cnt)
{
    int e = blockIdx.x * blockDim.x + threadIdx.x;
    atomicAdd(&cnt[hi[e]], 1);
}

__global__ void scan_kernel(const int* __restrict__ cnt, int* __restrict__ cur)
{
    __shared__ int part[1024];
    int t = threadIdx.x;
    int local[8]; int s = 0;
    #pragma unroll
    for (int k = 0; k < 8; k++) { local[k] = cnt[t * 8 + k]; s += local[k]; }
    part[t] = s;
    __syncthreads();
    for (int d = 1; d < 1024; d <<= 1) {
        int v = (t >= d) ? part[t - d] : 0;
        __syncthreads();
        part[t] += v;
        __syncthreads();
    }
    int base = t ? part[t - 1] : 0;
    #pragma unroll
    for (int k = 0; k < 8; k++) { cur[t * 8 + k] = base; base += local[k]; }
}

__global__ void scatter_kernel(const int* __restrict__ hi, const int* __restrict__ wi,
                               const float* __restrict__ actor_ctrs, const float* __restrict__ node_ctrs,
                               int* __restrict__ cur,
                               int* __restrict__ hi_s, int* __restrict__ wi_s,
                               float2* __restrict__ dxy_s)
{
    int e = blockIdx.x * blockDim.x + threadIdx.x;
    int h = hi[e], w = wi[e];
    int p = atomicAdd(&cur[h], 1);
    hi_s[p] = h; wi_s[p] = w;
    float2 a2 = ((const float2*)actor_ctrs)[h];
    float2 n2 = ((const float2*)node_ctrs)[w];
    dxy_s[p] = float2{a2.x - n2.x, a2.y - n2.y};
}

// ---- per-node precompute: nc = nodes @ Wc^T (ctx0 node-slice), SWIZZLED out. Zero barriers. ----
__global__ __launch_bounds__(256, 3) void nodec_kernel(
    const float* __restrict__ nodes, const bf16* __restrict__ Wn, bf16* __restrict__ nc)
{
    __shared__ __align__(16) bf16 AB[4 * 32 * AP];   // 34816 B
    int tid = threadIdx.x, wid = tid >> 6, lane = tid & 63, quad = lane >> 4, l16 = lane & 15;
    bf16* Aw = AB + wid * 32 * AP;
    int r0 = (blockIdx.x * 4 + wid) * 32;
    stage_rows_f32(nodes, r0, lane, Aw);
    f32x4 acc[2][8]; zero_acc(acc);
    gemm_gB(Wn, Aw, acc, lane, quad, l16);
    #pragma unroll
    for (int mt = 0; mt < 2; mt++)
        #pragma unroll
        for (int r = 0; r < 4; r++) {
            int row = r0 + mt * 16 + quad * 4 + r;
            bf16x8 pk;
            #pragma unroll
            for (int nt = 0; nt < 8; nt++) { bf16 t = __float2bfloat16(acc[mt][nt][r]); pk[nt] = *(short*)&t; }
            *(bf16x8*)(nc + (size_t)row * DD + l16 * 8) = pk;   // swizzled [row][l16*8+nt]
        }
}

// ---- per-actor precompute: A_acc = actors @ agt^T; q = relu(GN(actors @ query^T));
//      qc = q @ Wq^T. Zero barriers. ----
__global__ __launch_bounds__(256, 3) void prep_kernel(
    const float* __restrict__ actors_in,
    const bf16* __restrict__ Wag, const bf16* __restrict__ Wqu, const bf16* __restrict__ Wqc,
    const float* __restrict__ qg, const float* __restrict__ qb,
    bf16* __restrict__ qc, float* __restrict__ A_acc)
{
    __shared__ __align__(16) bf16 AB[4 * 32 * AP];
    int tid = threadIdx.x, wid = tid >> 6, lane = tid & 63, quad = lane >> 4, l16 = lane & 15;
    bf16* Aw = AB + wid * 32 * AP;
    int r0 = (blockIdx.x * 4 + wid) * 32;
    float qgv[8], qbv[8];
    #pragma unroll
    for (int nt = 0; nt < 8; nt++) { qgv[nt] = qg[nt * 16 + l16]; qbv[nt] = qb[nt * 16 + l16]; }
    stage_rows_f32(actors_in, r0, lane, Aw);
    f32x4 acc[2][8];
    // agt
    zero_acc(acc);
    gemm_gB(Wag, Aw, acc, lane, quad, l16);
    #pragma unroll
    for (int mt = 0; mt < 2; mt++)
        #pragma unroll
        for (int r = 0; r < 4; r++) {
            int row = r0 + mt * 16 + quad * 4 + r;
            #pragma unroll
            for (int nt = 0; nt < 8; nt++)
                A_acc[(size_t)row * DD + nt * 16 + l16] = acc[mt][nt][r];
        }
    // query -> GN+relu -> Aw
    zero_acc(acc);
    gemm_gB(Wqu, Aw, acc, lane, quad, l16);
    gn_relu(acc, qgv, qbv, Aw, quad, l16);
    // qc = q @ Wq^T, swizzled out
    zero_acc(acc);
    gemm_gB(Wqc, Aw, acc, lane, quad, l16);
    #pragma unroll
    for (int mt = 0; mt < 2; mt++)
        #pragma unroll
        for (int r = 0; r < 4; r++) {
            int row = r0 + mt * 16 + quad * 4 + r;
            bf16x8 pk;
            #pragma unroll
            for (int nt = 0; nt < 8; nt++) { bf16 t = __float2bfloat16(acc[mt][nt][r]); pk[nt] = *(short*)&t; }
            *(bf16x8*)(qc + (size_t)row * DD + l16 * 8) = pk;
        }
}

// ---- fused edge pipeline on SORTED edges: B from swizzled global, zero barriers. ----
__global__ __launch_bounds__(256, 2) void edge_kernel(
    const int* __restrict__ hi_s, const int* __restrict__ wi_s, const float2* __restrict__ dxy_s,
    const float* __restrict__ d0W, const float* __restrict__ d0b,
    const bf16* __restrict__ Wd1, const bf16* __restrict__ Wc0d, const bf16* __restrict__ Wc1,
    const float* __restrict__ d1g, const float* __restrict__ d1bb,
    const float* __restrict__ c0g, const float* __restrict__ c0bb,
    const bf16* __restrict__ qc, const bf16* __restrict__ nc,
    float* __restrict__ A_acc)
{
    __shared__ __align__(16) bf16 AB[4 * 32 * AP];   // 34816 B
    int tid = threadIdx.x, wid = tid >> 6, lane = tid & 63, quad = lane >> 4, l16 = lane & 15;
    bf16* Aw = AB + wid * 32 * AP;
    int e0 = (blockIdx.x * 4 + wid) * 32;

    // per-lane hoisted constants
    int ch = lane * 2;
    float w00 = d0W[ch * 2], w01 = d0W[ch * 2 + 1], bb0 = d0b[ch];
    float w10 = d0W[ch * 2 + 2], w11 = d0W[ch * 2 + 3], bb1 = d0b[ch + 1];
    float d1gv[8], d1bv[8], c0gv[8], c0bv[8];
    #pragma unroll
    for (int nt = 0; nt < 8; nt++) {
        d1gv[nt] = d1g[nt * 16 + l16];  d1bv[nt] = d1bb[nt * 16 + l16];
        c0gv[nt] = c0g[nt * 16 + l16];  c0bv[nt] = c0bb[nt * 16 + l16];
    }

    // meta via lane 0..31 loads + shuffles
    int hv = 0, wv = 0; float dxv = 0.f, dyv = 0.f;
    if (lane < 32) {
        int e = e0 + lane;
        hv = hi_s[e]; wv = wi_s[e];
        float2 d = dxy_s[e];
        dxv = d.x; dyv = d.y;
    }
    // stage0: h0 = relu(disp @ dist0^T + b0) -> Aw (2 ch x 32 rows per lane)
    #pragma unroll
    for (int rr = 0; rr < 32; rr++) {
        float dx = __shfl(dxv, rr), dy = __shfl(dyv, rr);
        float y0 = fmaxf(dx * w00 + dy * w01 + bb0, 0.f);
        float y1 = fmaxf(dx * w10 + dy * w11 + bb1, 0.f);
        __hip_bfloat162 p; p.x = __float2bfloat16(y0); p.y = __float2bfloat16(y1);
        *(__hip_bfloat162*)(Aw + rr * AP + ch) = p;
    }
    f32x4 acc[2][8];

    // dist1: d = relu(GN(h0 @ dist1^T))
    zero_acc(acc);
    gemm_gB(Wd1, Aw, acc, lane, quad, l16);
    gn_relu(acc, d1gv, d1bv, Aw, quad, l16);

    // ctx0: init = qc[hi] + nc[wi] (swizzled 16B gathers), += d @ Wd^T
    #pragma unroll
    for (int mt = 0; mt < 2; mt++)
        #pragma unroll
        for (int r = 0; r < 4; r++) {
            int row = mt * 16 + quad * 4 + r;
            int h = __shfl(hv, row), w = __shfl(wv, row);
            bf16x8 qv = *(const bf16x8*)(qc + (size_t)h * DD + l16 * 8);
            bf16x8 nv = *(const bf16x8*)(nc + (size_t)w * DD + l16 * 8);
            #pragma unroll
            for (int nt = 0; nt < 8; nt++)
                acc[mt][nt][r] = bf2f(qv[nt]) + bf2f(nv[nt]);
        }
    gemm_gB(Wc0d, Aw, acc, lane, quad, l16);
    gn_relu(acc, c0gv, c0bv, Aw, quad, l16);

    // ctx1 + run-merged atomic scatter into A_acc[hi]
    zero_acc(acc);
    gemm_gB(Wc1, Aw, acc, lane, quad, l16);
    #pragma unroll
    for (int mt = 0; mt < 2; mt++) {
        int base = mt * 16 + quad * 4;
        int curh = __shfl(hv, base);
        float run[8];
        #pragma unroll
        for (int nt = 0; nt < 8; nt++) run[nt] = acc[mt][nt][0];
        #pragma unroll
        for (int r = 1; r < 4; r++) {
            int hr = __shfl(hv, base + r);
            if (hr == curh) {
                #pragma unroll
                for (int nt = 0; nt < 8; nt++) run[nt] += acc[mt][nt][r];
            } else {
                float* dst = A_acc + (size_t)curh * DD + l16;
                #pragma unroll
                for (int nt = 0; nt < 8; nt++) atomicAdd(dst + nt * 16, run[nt]);
                curh = hr;
                #pragma unroll
                for (int nt = 0; nt < 8; nt++) run[nt] = acc[mt][nt][r];
            }
        }
        float* dst = A_acc + (size_t)curh * DD + l16;
        #pragma unroll
        for (int nt = 0; nt < 8; nt++) atomicAdd(dst + nt * 16, run[nt]);
    }
}

// ---- post: a=relu(GN(A_acc)); t=GN(a @ lin^T); out=relu(t + res). Zero barriers. ----
__global__ __launch_bounds__(256, 3) void post_kernel(
    const float* __restrict__ A_acc,
    const float* __restrict__ ng, const float* __restrict__ nb,
    const bf16* __restrict__ Wli, const float* __restrict__ lg, const float* __restrict__ lb,
    const float* __restrict__ resid, float* __restrict__ outp)
{
    __shared__ __align__(16) bf16 AB[4 * 32 * AP];
    int tid = threadIdx.x, wid = tid >> 6, lane = tid & 63, quad = lane >> 4, l16 = lane & 15;
    bf16* Aw = AB + wid * 32 * AP;
    int r0 = (blockIdx.x * 4 + wid) * 32;
    float lgv[8], lbv[8];
    #pragma unroll
    for (int nt = 0; nt < 8; nt++) { lgv[nt] = lg[nt * 16 + l16]; lbv[nt] = lb[nt * 16 + l16]; }

    // stage0: relu(GN(A_acc)) -> Aw
    {
        int half = lane >> 5, c4 = (lane & 31) * 4;
        float4 g4 = *(const float4*)(ng + c4);
        float4 b4 = *(const float4*)(nb + c4);
        #pragma unroll
        for (int it = 0; it < 16; it++) {
            int rr = it * 2 + half;
            float4 x = *(const float4*)(A_acc + (size_t)(r0 + rr) * DD + c4);
            float s1 = x.x + x.y + x.z + x.w;
            float s2 = x.x * x.x + x.y * x.y + x.z * x.z + x.w * x.w;
            #pragma unroll
            for (int m = 1; m < 32; m <<= 1) { s1 += __shfl_xor(s1, m, 64); s2 += __shfl_xor(s2, m, 64); }
            float mean = s1 * (1.f / 128.f);
            float sc = rsqrtf(s2 * (1.f / 128.f) - mean * mean + GN_EPS);
            short4 p;
            bf16 t0 = __float2bfloat16(fmaxf((x.x - mean) * sc * g4.x + b4.x, 0.f)); p.x = *(short*)&t0;
            bf16 t1 = __float2bfloat16(fmaxf((x.y - mean) * sc * g4.y + b4.y, 0.f)); p.y = *(short*)&t1;
            bf16 t2 = __float2bfloat16(fmaxf((x.z - mean) * sc * g4.z + b4.z, 0.f)); p.z = *(short*)&t2;
            bf16 t3 = __float2bfloat16(fmaxf((x.w - mean) * sc * g4.w + b4.w, 0.f)); p.w = *(short*)&t3;
            *(short4*)(Aw + rr * AP + c4) = p;
        }
    }
    f32x4 acc[2][8]; zero_acc(acc);
    gemm_gB(Wli, Aw, acc, lane, quad, l16);
    #pragma unroll
    for (int mt = 0; mt < 2; mt++)
        #pragma unroll
        for (int r = 0; r < 4; r++) {
            float s1 = 0.f, s2 = 0.f;
            #pragma unroll
            for (int nt = 0; nt < 8; nt++) { float v = acc[mt][nt][r]; s1 += v; s2 += v * v; }
            #pragma unroll
            for (int m = 1; m < 16; m <<= 1) { s1 += __shfl_xor(s1, m, 64); s2 += __shfl_xor(s2, m, 64); }
            float mean = s1 * (1.f / 128.f);
            float sc = rsqrtf(s2 * (1.f / 128.f) - mean * mean + GN_EPS);
            int row = r0 + mt * 16 + quad * 4 + r;
            #pragma unroll
            for (int nt = 0; nt < 8; nt++) {
                float y = (acc[mt][nt][r] - mean) * sc * lgv[nt] + lbv[nt];  // act=False before residual
                size_t o = (size_t)row * DD + nt * 16 + l16;
                outp[o] = fmaxf(y + resid[o], 0.f);
            }
        }
}

extern "C" void kernel_launch(void* const* d_in, const int* in_sizes, int n_in,
                              void* d_out, int out_size, void* d_ws, size_t ws_size,
                              hipStream_t stream)
{
    const float* actors     = (const float*)d_in[0];
    const float* nodes      = (const float*)d_in[1];
    const float* actor_ctrs = (const float*)d_in[2];
    const float* node_ctrs  = (const float*)d_in[3];
    const int*   hi         = (const int*)d_in[4];
    const int*   wi         = (const int*)d_in[5];
    const float* dist0_W    = (const float*)d_in[6];
    const float* dist0_b    = (const float*)d_in[7];
    const float* dist1_W    = (const float*)d_in[8];
    const float* dist1_g    = (const float*)d_in[9];
    const float* dist1_b    = (const float*)d_in[10];
    const float* query_W    = (const float*)d_in[11];
    const float* query_g    = (const float*)d_in[12];
    const float* query_b    = (const float*)d_in[13];
    const float* ctx0_W     = (const float*)d_in[14];
    const float* ctx0_g     = (const float*)d_in[15];
    const float* ctx0_b     = (const float*)d_in[16];
    const float* ctx1_W     = (const float*)d_in[17];
    const float* agt_W      = (const float*)d_in[18];
    const float* norm_g     = (const float*)d_in[19];
    const float* norm_b     = (const float*)d_in[20];
    const float* lin_W      = (const float*)d_in[21];
    const float* lin_g      = (const float*)d_in[22];
    const float* lin_b      = (const float*)d_in[23];

    // workspace layout (~30.6 MB)
    char* ws = (char*)d_ws;
    size_t off = 0;
    bf16*  Wp         = (bf16*)(ws + off);  off += 524288;      // 16 packed tiles (512 KB)
    float* A_acc      = (float*)(ws + off); off += 4194304;     // 4 MB
    float* actors_mid = (float*)(ws + off); off += 4194304;     // 4 MB
    bf16*  qc_bf      = (bf16*)(ws + off);  off += 2097152;     // 2 MB
    bf16*  nc_bf      = (bf16*)(ws + off);  off += 16777216;    // 16 MB
    int*   cnt        = (int*)(ws + off);   off += 32768;
    int*   cur        = (int*)(ws + off);   off += 32768;
    int*   hi_s       = (int*)(ws + off);   off += 1048576;
    int*   wi_s       = (int*)(ws + off);   off += 1048576;
    float2* dxy_s     = (float2*)(ws + off); off += 2097152;

    pack_w_kernel<<<128, 256, 0, stream>>>(dist1_W, query_W, ctx0_W, ctx1_W, agt_W, lin_W, Wp);

    // counting sort by hi (shared by both Att blocks)
    zero_cnt_kernel<<<32, 256, 0, stream>>>(cnt);
    hist_kernel<<<NEG / 256, 256, 0, stream>>>(hi, cnt);
    scan_kernel<<<1, 1024, 0, stream>>>(cnt, cur);
    scatter_kernel<<<NEG / 256, 256, 0, stream>>>(hi, wi, actor_ctrs, node_ctrs,
                                                  cur, hi_s, wi_s, dxy_s);

    for (int i = 0; i < 2; i++) {
        const bf16* T = Wp + (size_t)i * 8 * TSZ;   // tiles: 0=d1 1=qu 2=c0d 3=c0q 4=c0n 5=c1 6=ag 7=li
        const float* curp = i ? actors_mid : actors;
        float* nxt = i ? (float*)d_out : actors_mid;

        nodec_kernel<<<NND / 128, 256, 0, stream>>>(nodes, T + 4 * TSZ, nc_bf);
        prep_kernel<<<NAC / 128, 256, 0, stream>>>(curp,
            T + 6 * TSZ, T + 1 * TSZ, T + 3 * TSZ,
            query_g + i * 128, query_b + i * 128, qc_bf, A_acc);
        edge_kernel<<<NEG / 128, 256, 0, stream>>>(hi_s, wi_s, dxy_s,
            dist0_W + i * 256, dist0_b + i * 128,
            T + 0 * TSZ, T + 2 * TSZ, T + 5 * TSZ,
            dist1_g + i * 128, dist1_b + i * 128,
            ctx0_g + i * 128, ctx0_b + i * 128,
            qc_bf, nc_bf, A_acc);
        post_kernel<<<NAC / 128, 256, 0, stream>>>(A_acc, norm_g + i * 128, norm_b + i * 128,
            T + 7 * TSZ, lin_g + i * 128, lin_b + i * 128, curp, nxt);
    }
}